// Round 1
// baseline (135.210 us; speedup 1.0000x reference)
//
#include <hip/hip_runtime.h>

// ParaModel_69664369541839: match = v1 @ v2^T [B,L1,L2]; masked row/col max;
// s = -max/100 masked; softmax; attention-pool p1,p2; cosine(p1,p2).
// B=128, L1=L2=256, D=768, fp32 in/out.
//
// R0 design: fp16 MFMA (16x16x32) for the match GEMM (precision margin ~20x vs
// threshold; bf16 would be marginal). Row/col maxes via monotone-uint atomicMax
// (never materialize the 33MB match matrix). Then softmax+pool, then cosine.

#define B_   128
#define L_   256
#define D_   768
#define NEGV (-10000.0f)

typedef _Float16 f16x8 __attribute__((ext_vector_type(8)));
typedef _Float16 f16x4 __attribute__((ext_vector_type(4)));
typedef float    f32x4 __attribute__((ext_vector_type(4)));

#define BT  64   // l1/l2 tile
#define BK  32   // k tile
#define LDT 40   // LDS row stride in halves (pad 32->40: 80B, 16B-aligned, 2-way max)

__device__ __forceinline__ unsigned fmap(float f) {
    unsigned u = __float_as_uint(f);
    return (u & 0x80000000u) ? ~u : (u | 0x80000000u);   // monotone float->uint
}
__device__ __forceinline__ float fdecode(unsigned u) {
    return __uint_as_float((u & 0x80000000u) ? (u ^ 0x80000000u) : ~u);
}

__device__ __forceinline__ float wred_max(float v) {
    #pragma unroll
    for (int o = 32; o; o >>= 1) v = fmaxf(v, __shfl_xor(v, o));
    return v;
}
__device__ __forceinline__ float wred_sum(float v) {
    #pragma unroll
    for (int o = 32; o; o >>= 1) v += __shfl_xor(v, o);
    return v;
}

// K1: per (b, ti, tj): 64x64 match tile via MFMA; masked row/col max -> global atomics.
__global__ __launch_bounds__(256)
void k_match_max(const float* __restrict__ v1, const float* __restrict__ m1,
                 const float* __restrict__ v2, const float* __restrict__ m2,
                 unsigned* __restrict__ ru1, unsigned* __restrict__ ru2)
{
    __shared__ __align__(16) _Float16 As[BT][LDT];
    __shared__ __align__(16) _Float16 Bs[BT][LDT];
    __shared__ unsigned rU[BT], cU[BT];
    __shared__ float m1s[BT], m2s[BT];

    const int tj = blockIdx.x, ti = blockIdx.y, b = blockIdx.z;
    const int t = threadIdx.x;
    const int lane = t & 63, w = t >> 6;
    const int wr = w >> 1, wc = w & 1;          // wave quadrant in 64x64
    const int fr = lane & 15, fg = lane >> 4;   // fragment row/col & k-group

    if (t < BT) {
        rU[t] = 0u; cU[t] = 0u;                 // 0 == fmap(-NaN) == -inf identity
        m1s[t] = m1[b * L_ + ti * BT + t];
        m2s[t] = m2[b * L_ + tj * BT + t];
    }

    const float* pa = v1 + ((size_t)b * L_ + ti * BT) * D_;
    const float* pb = v2 + ((size_t)b * L_ + tj * BT) * D_;

    f32x4 acc[2][2] = {};
    for (int k0 = 0; k0 < D_; k0 += BK) {
        __syncthreads();
        #pragma unroll
        for (int rr = 0; rr < 2; ++rr) {        // 512 float4 loads per operand tile
            int idx = t + rr * 256;
            int row = idx >> 3;
            int kq  = (idx & 7) << 2;
            float4 a4 = *(const float4*)(pa + (size_t)row * D_ + k0 + kq);
            float4 b4 = *(const float4*)(pb + (size_t)row * D_ + k0 + kq);
            f16x4 ah = { (_Float16)a4.x, (_Float16)a4.y, (_Float16)a4.z, (_Float16)a4.w };
            f16x4 bh = { (_Float16)b4.x, (_Float16)b4.y, (_Float16)b4.z, (_Float16)b4.w };
            *(f16x4*)&As[row][kq] = ah;
            *(f16x4*)&Bs[row][kq] = bh;
        }
        __syncthreads();
        f16x8 af[2], bf[2];
        af[0] = *(const f16x8*)&As[wr * 32 +      fr][fg * 8];
        af[1] = *(const f16x8*)&As[wr * 32 + 16 + fr][fg * 8];
        bf[0] = *(const f16x8*)&Bs[wc * 32 +      fr][fg * 8];
        bf[1] = *(const f16x8*)&Bs[wc * 32 + 16 + fr][fg * 8];
        #pragma unroll
        for (int i = 0; i < 2; ++i)
            #pragma unroll
            for (int j = 0; j < 2; ++j)
                acc[i][j] = __builtin_amdgcn_mfma_f32_16x16x32_f16(af[i], bf[j], acc[i][j], 0, 0, 0);
    }

    // masked row-max (over this tile's 64 cols) and col-max (over 64 rows)
    float m2v0 = m2s[wc * 32 +      fr];
    float m2v1 = m2s[wc * 32 + 16 + fr];
    #pragma unroll
    for (int i = 0; i < 2; ++i) {
        #pragma unroll
        for (int r = 0; r < 4; ++r) {
            int row = wr * 32 + i * 16 + fg * 4 + r;
            bool rv = m1s[row] > 0.f;
            float a = (rv && m2v0 > 0.f) ? acc[i][0][r] : NEGV;
            float c = (rv && m2v1 > 0.f) ? acc[i][1][r] : NEGV;
            atomicMax(&rU[row], fmap(fmaxf(a, c)));
        }
    }
    #pragma unroll
    for (int j = 0; j < 2; ++j) {
        int col = wc * 32 + j * 16 + fr;
        bool cv = m2s[col] > 0.f;
        float cm = NEGV;
        #pragma unroll
        for (int i = 0; i < 2; ++i)
            #pragma unroll
            for (int r = 0; r < 4; ++r) {
                int row = wr * 32 + i * 16 + fg * 4 + r;
                float vv = (cv && m1s[row] > 0.f) ? acc[i][j][r] : NEGV;
                cm = fmaxf(cm, vv);
            }
        atomicMax(&cU[col], fmap(cm));
    }
    __syncthreads();
    if (t < 64)        atomicMax(&ru1[b * L_ + ti * 64 + t],        rU[t]);
    else if (t < 128)  atomicMax(&ru2[b * L_ + tj * 64 + (t - 64)], cU[t - 64]);
}

// K2: per (b, side, chunk-of-256-dims): softmax over 256 logits + weighted pool.
__global__ __launch_bounds__(256)
void k_attn_pool(const float* __restrict__ v1, const float* __restrict__ m1,
                 const float* __restrict__ v2, const float* __restrict__ m2,
                 const unsigned* __restrict__ ru1, const unsigned* __restrict__ ru2,
                 float* __restrict__ pout)
{
    const int b = blockIdx.x, side = blockIdx.y, chunk = blockIdx.z;
    const float* v      = side ? v2 : v1;
    const float* mk     = side ? m2 : m1;
    const unsigned* ru  = side ? ru2 : ru1;
    const int t = threadIdx.x, lane = t & 63, w = t >> 6;

    __shared__ float attn[L_];
    __shared__ float sred[4];

    float mkv = mk[b * L_ + t];
    float mxv = fdecode(ru[b * L_ + t]);
    float s = (mkv > 0.f) ? (-mxv / 100.0f) : NEGV;

    float wm = wred_max(s);
    if (lane == 0) sred[w] = wm;
    __syncthreads();
    float mx = fmaxf(fmaxf(sred[0], sred[1]), fmaxf(sred[2], sred[3]));
    float e = expf(s - mx);
    __syncthreads();
    float ws = wred_sum(e);
    if (lane == 0) sred[w] = ws;
    __syncthreads();
    float sum = sred[0] + sred[1] + sred[2] + sred[3];
    attn[t] = e / sum;
    __syncthreads();

    const int d = chunk * 256 + t;
    const float* vb = v + (size_t)b * L_ * D_ + d;
    float p = 0.f;
    #pragma unroll 8
    for (int l = 0; l < L_; ++l) p += attn[l] * vb[(size_t)l * D_];
    pout[((size_t)b * 2 + side) * D_ + d] = p;
}

// K3: per batch: cosine similarity of p1, p2.
__global__ __launch_bounds__(256)
void k_cos(const float* __restrict__ pout, float* __restrict__ out)
{
    const int b = blockIdx.x, t = threadIdx.x, lane = t & 63, w = t >> 6;
    const float* p1 = pout + (size_t)b * 2 * D_;
    const float* p2 = p1 + D_;
    float dot = 0.f, n1 = 0.f, n2 = 0.f;
    for (int d = t; d < D_; d += 256) {
        float a = p1[d], c = p2[d];
        dot += a * c; n1 += a * a; n2 += c * c;
    }
    dot = wred_sum(dot); n1 = wred_sum(n1); n2 = wred_sum(n2);
    __shared__ float sd[4], sa[4], sc[4];
    if (lane == 0) { sd[w] = dot; sa[w] = n1; sc[w] = n2; }
    __syncthreads();
    if (t == 0) {
        float dd = sd[0] + sd[1] + sd[2] + sd[3];
        float aa = sa[0] + sa[1] + sa[2] + sa[3];
        float cc = sc[0] + sc[1] + sc[2] + sc[3];
        out[b] = dd / (fmaxf(sqrtf(aa), 1e-8f) * fmaxf(sqrtf(cc), 1e-8f));
    }
}

extern "C" void kernel_launch(void* const* d_in, const int* in_sizes, int n_in,
                              void* d_out, int out_size, void* d_ws, size_t ws_size,
                              hipStream_t stream)
{
    const float* v1 = (const float*)d_in[0];
    const float* m1 = (const float*)d_in[1];
    const float* v2 = (const float*)d_in[2];
    const float* m2 = (const float*)d_in[3];
    float* out = (float*)d_out;

    unsigned* ru1 = (unsigned*)d_ws;                 // [B, L] mapped row-max (side 1)
    unsigned* ru2 = ru1 + (size_t)B_ * L_;           // [B, L] mapped col-max (side 2)
    float*    pout = (float*)(ru2 + (size_t)B_ * L_);// [B, 2, D] pooled vectors

    hipMemsetAsync(d_ws, 0, 2 * (size_t)B_ * L_ * sizeof(unsigned), stream);

    dim3 g1(L_ / BT, L_ / BT, B_);
    k_match_max<<<g1, 256, 0, stream>>>(v1, m1, v2, m2, ru1, ru2);

    dim3 g2(B_, 2, D_ / 256);
    k_attn_pool<<<g2, 256, 0, stream>>>(v1, m1, v2, m2, ru1, ru2, pout);

    k_cos<<<B_, 256, 0, stream>>>(pout, out);
}

// Round 2
// 82.970 us; speedup vs baseline: 1.6296x; 1.6296x over previous
//
#include <hip/hip_runtime.h>

// ParaModel_69664369541839: match = v1 @ v2^T [B,L1,L2]; masked row/col max;
// s = -max/100 masked; softmax; attention-pool p1,p2; cosine(p1,p2).
// B=128, L1=L2=256, D=768, fp32 in/out.
//
// R1: K1 rewritten — 128x128 tile (reuse 2 not 4), BK=64, register prefetch of
// next k-tile under current MFMA (fixes the ~1KB-in-flight latency bound seen
// at 2.9TB/s), T2 XOR swizzle on LDS (16-lane bank pileup -> wave64 floor),
// bijective XCD swizzle (4 blocks of a batch share one XCD's L2).

#define B_   128
#define L_   256
#define D_   768
#define NEGV (-10000.0f)

typedef _Float16 f16x8 __attribute__((ext_vector_type(8)));
typedef float    f32x4 __attribute__((ext_vector_type(4)));

#define BT   128          // l1/l2 tile
#define BKH  64           // K per LDS tile (fp32 elems / halves per row)
#define NKT  (D_ / BKH)   // 12

__device__ __forceinline__ unsigned fmap(float f) {
    unsigned u = __float_as_uint(f);
    return (u & 0x80000000u) ? ~u : (u | 0x80000000u);   // monotone float->uint
}
__device__ __forceinline__ float fdecode(unsigned u) {
    return __uint_as_float((u & 0x80000000u) ? (u ^ 0x80000000u) : ~u);
}
__device__ __forceinline__ float wred_max(float v) {
    #pragma unroll
    for (int o = 32; o; o >>= 1) v = fmaxf(v, __shfl_xor(v, o));
    return v;
}
__device__ __forceinline__ float wred_sum(float v) {
    #pragma unroll
    for (int o = 32; o; o >>= 1) v += __shfl_xor(v, o);
    return v;
}

// K1: per (b, ti, tj): 128x128 match tile via fp16 MFMA; masked row/col max.
__global__ __launch_bounds__(256, 2)
void k_match_max(const float* __restrict__ v1, const float* __restrict__ m1,
                 const float* __restrict__ v2, const float* __restrict__ m2,
                 unsigned* __restrict__ ru1, unsigned* __restrict__ ru2)
{
    __shared__ __align__(16) _Float16 As[BT * BKH];   // XOR-swizzled 16B blocks
    __shared__ __align__(16) _Float16 Bs[BT * BKH];
    __shared__ unsigned rU[BT], cU[BT];
    __shared__ float m1s[BT], m2s[BT];

    // bijective XCD swizzle: 512 blocks, 64 per XCD -> 16 consecutive batches/XCD
    const int nwg = gridDim.x;
    const int cpx = nwg >> 3;
    const int wg  = (blockIdx.x & 7) * cpx + (blockIdx.x >> 3);
    const int b = wg >> 2, ti = (wg >> 1) & 1, tj = wg & 1;

    const int t = threadIdx.x;
    const int lane = t & 63, w = t >> 6;
    const int wr = w >> 1, wc = w & 1;          // wave quadrant (64x64) in 128x128
    const int fr = lane & 15, fg = lane >> 4;

    if (t < BT) {
        rU[t] = 0u; cU[t] = 0u;                 // 0 == -inf under fmap
        m1s[t] = m1[b * L_ + ti * BT + t];
        m2s[t] = m2[b * L_ + tj * BT + t];
    }

    const float* pa = v1 + ((size_t)b * L_ + ti * BT) * D_;
    const float* pb = v2 + ((size_t)b * L_ + tj * BT) * D_;

    float4 ra[4][2], rb[4][2];                  // 16 float4 in flight per thread

    #define LOADT(kt)                                                         \
        _Pragma("unroll")                                                     \
        for (int rr = 0; rr < 4; ++rr) {                                      \
            int idx = rr * 256 + t;             /* 0..1023: row*8 + blk */    \
            int row = idx >> 3;                                               \
            int cf  = (kt) * BKH + ((idx & 7) << 3);                          \
            const float* A  = pa + (size_t)row * D_ + cf;                     \
            const float* Bp = pb + (size_t)row * D_ + cf;                     \
            ra[rr][0] = *(const float4*)A;  ra[rr][1] = *(const float4*)(A + 4);  \
            rb[rr][0] = *(const float4*)Bp; rb[rr][1] = *(const float4*)(Bp + 4); \
        }

    f32x4 acc[4][4] = {};
    LOADT(0);
    for (int kt = 0; kt < NKT; ++kt) {
        __syncthreads();                         // LDS free (covers init on kt=0)
        #pragma unroll
        for (int rr = 0; rr < 4; ++rr) {         // convert + swizzled store
            int idx = rr * 256 + t;
            int row = idx >> 3;
            int blk = (idx & 7) ^ (row & 7);
            f16x8 ah, bh;
            #pragma unroll
            for (int q = 0; q < 4; ++q) {
                ah[q]     = (_Float16)ra[rr][0][q]; ah[4 + q] = (_Float16)ra[rr][1][q];
                bh[q]     = (_Float16)rb[rr][0][q]; bh[4 + q] = (_Float16)rb[rr][1][q];
            }
            *(f16x8*)&As[row * BKH + blk * 8] = ah;
            *(f16x8*)&Bs[row * BKH + blk * 8] = bh;
        }
        __syncthreads();
        if (kt + 1 < NKT) { LOADT(kt + 1); }     // prefetch under MFMA
        #pragma unroll
        for (int ks = 0; ks < 2; ++ks) {
            f16x8 af[4], bf[4];
            #pragma unroll
            for (int i = 0; i < 4; ++i) {
                int r1 = wr * 64 + i * 16 + fr;
                int r2 = wc * 64 + i * 16 + fr;
                af[i] = *(const f16x8*)&As[r1 * BKH + (((ks * 4 + fg) ^ (r1 & 7)) << 3)];
                bf[i] = *(const f16x8*)&Bs[r2 * BKH + (((ks * 4 + fg) ^ (r2 & 7)) << 3)];
            }
            #pragma unroll
            for (int i = 0; i < 4; ++i)
                #pragma unroll
                for (int j = 0; j < 4; ++j)
                    acc[i][j] = __builtin_amdgcn_mfma_f32_16x16x32_f16(af[i], bf[j], acc[i][j], 0, 0, 0);
        }
    }
    #undef LOADT

    // masked row-max: C/D layout row = fg*4+reg (+16i), col = fr (+16j)
    #pragma unroll
    for (int i = 0; i < 4; ++i)
        #pragma unroll
        for (int r = 0; r < 4; ++r) {
            int row = wr * 64 + i * 16 + fg * 4 + r;
            bool rv = m1s[row] > 0.f;
            float mx = NEGV;
            #pragma unroll
            for (int j = 0; j < 4; ++j) {
                int col = wc * 64 + j * 16 + fr;
                float vv = (rv && m2s[col] > 0.f) ? acc[i][j][r] : NEGV;
                mx = fmaxf(mx, vv);
            }
            atomicMax(&rU[row], fmap(mx));
        }
    // masked col-max
    #pragma unroll
    for (int j = 0; j < 4; ++j) {
        int col = wc * 64 + j * 16 + fr;
        bool cv = m2s[col] > 0.f;
        float mx = NEGV;
        #pragma unroll
        for (int i = 0; i < 4; ++i)
            #pragma unroll
            for (int r = 0; r < 4; ++r) {
                int row = wr * 64 + i * 16 + fg * 4 + r;
                float vv = (cv && m1s[row] > 0.f) ? acc[i][j][r] : NEGV;
                mx = fmaxf(mx, vv);
            }
        atomicMax(&cU[col], fmap(mx));
    }
    __syncthreads();
    if (t < BT) atomicMax(&ru1[b * L_ + ti * BT + t], rU[t]);
    else        atomicMax(&ru2[b * L_ + tj * BT + (t - BT)], cU[t - BT]);
}

// K2: per (b, side): softmax over 256 logits + pool; thread owns cols t, t+256, t+512.
__global__ __launch_bounds__(256)
void k_attn_pool(const float* __restrict__ v1, const float* __restrict__ m1,
                 const float* __restrict__ v2, const float* __restrict__ m2,
                 const unsigned* __restrict__ ru1, const unsigned* __restrict__ ru2,
                 float* __restrict__ pout)
{
    const int b = blockIdx.x, side = blockIdx.y;
    const float* v     = side ? v2 : v1;
    const float* mk    = side ? m2 : m1;
    const unsigned* ru = side ? ru2 : ru1;
    const int t = threadIdx.x, lane = t & 63, w = t >> 6;

    __shared__ float attn[L_];
    __shared__ float sred[4];

    float mkv = mk[b * L_ + t];
    float s = (mkv > 0.f) ? (-fdecode(ru[b * L_ + t]) / 100.0f) : NEGV;

    float wm = wred_max(s);
    if (lane == 0) sred[w] = wm;
    __syncthreads();
    float mx = fmaxf(fmaxf(sred[0], sred[1]), fmaxf(sred[2], sred[3]));
    float e = expf(s - mx);
    __syncthreads();
    float ws = wred_sum(e);
    if (lane == 0) sred[w] = ws;
    __syncthreads();
    float sum = sred[0] + sred[1] + sred[2] + sred[3];
    attn[t] = e / sum;
    __syncthreads();

    const float* vb = v + (size_t)b * L_ * D_;
    float p0 = 0.f, p1 = 0.f, p2 = 0.f;
    #pragma unroll 4
    for (int l = 0; l < L_; ++l) {
        float a = attn[l];
        const float* r = vb + (size_t)l * D_;
        p0 += a * r[t];
        p1 += a * r[t + 256];
        p2 += a * r[t + 512];
    }
    float* po = pout + ((size_t)b * 2 + side) * D_;
    po[t] = p0; po[t + 256] = p1; po[t + 512] = p2;
}

// K3: per batch: cosine similarity of p1, p2.
__global__ __launch_bounds__(256)
void k_cos(const float* __restrict__ pout, float* __restrict__ out)
{
    const int b = blockIdx.x, t = threadIdx.x, lane = t & 63, w = t >> 6;
    const float* p1 = pout + (size_t)b * 2 * D_;
    const float* p2 = p1 + D_;
    float dot = 0.f, n1 = 0.f, n2 = 0.f;
    for (int d = t; d < D_; d += 256) {
        float a = p1[d], c = p2[d];
        dot += a * c; n1 += a * a; n2 += c * c;
    }
    dot = wred_sum(dot); n1 = wred_sum(n1); n2 = wred_sum(n2);
    __shared__ float sd[4], sa[4], sc[4];
    if (lane == 0) { sd[w] = dot; sa[w] = n1; sc[w] = n2; }
    __syncthreads();
    if (t == 0) {
        float dd = sd[0] + sd[1] + sd[2] + sd[3];
        float aa = sa[0] + sa[1] + sa[2] + sa[3];
        float cc = sc[0] + sc[1] + sc[2] + sc[3];
        out[b] = dd / (fmaxf(sqrtf(aa), 1e-8f) * fmaxf(sqrtf(cc), 1e-8f));
    }
}

extern "C" void kernel_launch(void* const* d_in, const int* in_sizes, int n_in,
                              void* d_out, int out_size, void* d_ws, size_t ws_size,
                              hipStream_t stream)
{
    const float* v1 = (const float*)d_in[0];
    const float* m1 = (const float*)d_in[1];
    const float* v2 = (const float*)d_in[2];
    const float* m2 = (const float*)d_in[3];
    float* out = (float*)d_out;

    unsigned* ru1 = (unsigned*)d_ws;                  // [B, L] mapped row-max (side 1)
    unsigned* ru2 = ru1 + (size_t)B_ * L_;            // [B, L] mapped col-max (side 2)
    float*    pout = (float*)(ru2 + (size_t)B_ * L_); // [B, 2, D] pooled vectors

    hipMemsetAsync(d_ws, 0, 2 * (size_t)B_ * L_ * sizeof(unsigned), stream);

    k_match_max<<<dim3((L_ / BT) * (L_ / BT) * B_), 256, 0, stream>>>(v1, m1, v2, m2, ru1, ru2);

    dim3 g2(B_, 2);
    k_attn_pool<<<g2, 256, 0, stream>>>(v1, m1, v2, m2, ru1, ru2, pout);

    k_cos<<<B_, 256, 0, stream>>>(pout, out);
}

// Round 3
// 80.283 us; speedup vs baseline: 1.6842x; 1.0335x over previous
//
#include <hip/hip_runtime.h>

// ParaModel_69664369541839: match = v1 @ v2^T [B,L1,L2]; masked row/col max;
// s = -max/100 masked; softmax; attention-pool p1,p2; cosine(p1,p2).
// B=128, L1=L2=256, D=768, fp32 in/out.
//
// R3: K1 = 512-thread 128x128 tile (8 waves of 32x64), register prefetch kept
// alive via low per-wave acc (32 VGPR) + sched_barrier(0) pin (R2's compiler
// sank the prefetch -> latency-bound at VGPR=116). K2 back to 768 blocks.
// Bijective XCD swizzle on K1+K2.

#define B_   128
#define L_   256
#define D_   768
#define NEGV (-10000.0f)

typedef _Float16 f16x8 __attribute__((ext_vector_type(8)));
typedef float    f32x4 __attribute__((ext_vector_type(4)));

#define BT   128          // l1/l2 tile
#define BKH  64           // K per LDS tile
#define NKT  (D_ / BKH)   // 12

__device__ __forceinline__ unsigned fmap(float f) {
    unsigned u = __float_as_uint(f);
    return (u & 0x80000000u) ? ~u : (u | 0x80000000u);   // monotone float->uint
}
__device__ __forceinline__ float fdecode(unsigned u) {
    return __uint_as_float((u & 0x80000000u) ? (u ^ 0x80000000u) : ~u);
}
__device__ __forceinline__ float wred_max(float v) {
    #pragma unroll
    for (int o = 32; o; o >>= 1) v = fmaxf(v, __shfl_xor(v, o));
    return v;
}
__device__ __forceinline__ float wred_sum(float v) {
    #pragma unroll
    for (int o = 32; o; o >>= 1) v += __shfl_xor(v, o);
    return v;
}

// K1: per (b, ti, tj): 128x128 match tile via fp16 MFMA; masked row/col max.
__global__ __launch_bounds__(512, 4)
void k_match_max(const float* __restrict__ v1, const float* __restrict__ m1,
                 const float* __restrict__ v2, const float* __restrict__ m2,
                 unsigned* __restrict__ ru1, unsigned* __restrict__ ru2)
{
    __shared__ __align__(16) _Float16 As[BT * BKH];   // XOR-swizzled 16B blocks
    __shared__ __align__(16) _Float16 Bs[BT * BKH];
    __shared__ unsigned rU[BT], cU[BT];
    __shared__ float m1s[BT], m2s[BT];

    // bijective XCD swizzle: 512 blocks, 64/XCD -> a batch's 4 blocks on one XCD
    const int bid = blockIdx.x;
    const int wg  = (bid & 7) * 64 + (bid >> 3);
    const int b = wg >> 2, ti = (wg >> 1) & 1, tj = wg & 1;

    const int t = threadIdx.x;
    const int lane = t & 63, w = t >> 6;
    const int wr = w >> 1, wc = w & 1;          // wave sub-tile: 32 rows x 64 cols
    const int fr = lane & 15, fg = lane >> 4;

    if (t < BT) {
        rU[t] = 0u; cU[t] = 0u;                 // 0 == -inf under fmap
        m1s[t] = m1[b * L_ + ti * BT + t];
        m2s[t] = m2[b * L_ + tj * BT + t];
    }

    const float* pa = v1 + ((size_t)b * L_ + ti * BT) * D_;
    const float* pb = v2 + ((size_t)b * L_ + tj * BT) * D_;

    float4 ra[2][2], rb[2][2];                  // 8 float4 in flight per thread

    #define LOADT(kt)                                                          \
        _Pragma("unroll")                                                      \
        for (int g = 0; g < 2; ++g) {                                          \
            int idx = g * 512 + t;              /* 0..1023: row*8 + blk */     \
            int row = idx >> 3;                                                \
            int cf  = (kt) * BKH + ((idx & 7) << 3);                           \
            const float* A  = pa + (size_t)row * D_ + cf;                      \
            const float* Bp = pb + (size_t)row * D_ + cf;                      \
            ra[g][0] = *(const float4*)A;  ra[g][1] = *(const float4*)(A + 4); \
            rb[g][0] = *(const float4*)Bp; rb[g][1] = *(const float4*)(Bp + 4);\
        }

    f32x4 acc[2][4] = {};
    LOADT(0);
    for (int kt = 0; kt < NKT; ++kt) {
        __syncthreads();                         // LDS free (covers init on kt=0)
        #pragma unroll
        for (int g = 0; g < 2; ++g) {            // convert + swizzled store
            int idx = g * 512 + t;
            int row = idx >> 3;
            int blk = (idx & 7) ^ (row & 7);
            f16x8 ah, bh;
            #pragma unroll
            for (int q = 0; q < 4; ++q) {
                ah[q] = (_Float16)ra[g][0][q]; ah[4 + q] = (_Float16)ra[g][1][q];
                bh[q] = (_Float16)rb[g][0][q]; bh[4 + q] = (_Float16)rb[g][1][q];
            }
            *(f16x8*)&As[row * BKH + blk * 8] = ah;
            *(f16x8*)&Bs[row * BKH + blk * 8] = bh;
        }
        __syncthreads();
        if (kt + 1 < NKT) { LOADT(kt + 1); }     // prefetch under MFMA...
        __builtin_amdgcn_sched_barrier(0);       // ...and PIN it there
        #pragma unroll
        for (int ks = 0; ks < 2; ++ks) {
            f16x8 af[2], bf[4];
            #pragma unroll
            for (int i = 0; i < 2; ++i) {
                int r1 = wr * 32 + i * 16 + fr;
                af[i] = *(const f16x8*)&As[r1 * BKH + (((ks * 4 + fg) ^ (r1 & 7)) << 3)];
            }
            #pragma unroll
            for (int j = 0; j < 4; ++j) {
                int r2 = wc * 64 + j * 16 + fr;
                bf[j] = *(const f16x8*)&Bs[r2 * BKH + (((ks * 4 + fg) ^ (r2 & 7)) << 3)];
            }
            #pragma unroll
            for (int i = 0; i < 2; ++i)
                #pragma unroll
                for (int j = 0; j < 4; ++j)
                    acc[i][j] = __builtin_amdgcn_mfma_f32_16x16x32_f16(af[i], bf[j], acc[i][j], 0, 0, 0);
        }
    }
    #undef LOADT

    // masked row-max: C/D layout row = fg*4+reg (+16i), col = fr (+16j)
    #pragma unroll
    for (int i = 0; i < 2; ++i)
        #pragma unroll
        for (int r = 0; r < 4; ++r) {
            int row = wr * 32 + i * 16 + fg * 4 + r;
            bool rv = m1s[row] > 0.f;
            float mx = NEGV;
            #pragma unroll
            for (int j = 0; j < 4; ++j) {
                int col = wc * 64 + j * 16 + fr;
                float vv = (rv && m2s[col] > 0.f) ? acc[i][j][r] : NEGV;
                mx = fmaxf(mx, vv);
            }
            atomicMax(&rU[row], fmap(mx));
        }
    // masked col-max
    #pragma unroll
    for (int j = 0; j < 4; ++j) {
        int col = wc * 64 + j * 16 + fr;
        bool cv = m2s[col] > 0.f;
        float mx = NEGV;
        #pragma unroll
        for (int i = 0; i < 2; ++i)
            #pragma unroll
            for (int r = 0; r < 4; ++r) {
                int row = wr * 32 + i * 16 + fg * 4 + r;
                float vv = (cv && m1s[row] > 0.f) ? acc[i][j][r] : NEGV;
                mx = fmaxf(mx, vv);
            }
        atomicMax(&cU[col], fmap(mx));
    }
    __syncthreads();
    if (t < BT)            atomicMax(&ru1[b * L_ + ti * BT + t], rU[t]);
    else if (t < 2 * BT)   atomicMax(&ru2[b * L_ + tj * BT + (t - BT)], cU[t - BT]);
}

// K2: per (b, side, chunk): softmax over 256 logits (redundant per chunk, cheap)
// + pool of 256 cols. 768 blocks.
__global__ __launch_bounds__(256)
void k_attn_pool(const float* __restrict__ v1, const float* __restrict__ m1,
                 const float* __restrict__ v2, const float* __restrict__ m2,
                 const unsigned* __restrict__ ru1, const unsigned* __restrict__ ru2,
                 float* __restrict__ pout)
{
    // XCD swizzle: 768 blocks -> 96/XCD -> 16 consecutive batches per XCD
    const int lin = (int)blockIdx.x;
    const int swz = (lin & 7) * 96 + (lin >> 3);
    const int b = swz / 6, rem = swz % 6, side = rem / 3, chunk = rem % 3;

    const float* v     = side ? v2 : v1;
    const float* mk    = side ? m2 : m1;
    const unsigned* ru = side ? ru2 : ru1;
    const int t = threadIdx.x, lane = t & 63, w = t >> 6;

    __shared__ float attn[L_];
    __shared__ float sred[4];

    float mkv = mk[b * L_ + t];
    float s = (mkv > 0.f) ? (-fdecode(ru[b * L_ + t]) / 100.0f) : NEGV;

    float wm = wred_max(s);
    if (lane == 0) sred[w] = wm;
    __syncthreads();
    float mx = fmaxf(fmaxf(sred[0], sred[1]), fmaxf(sred[2], sred[3]));
    float e = expf(s - mx);
    __syncthreads();
    float ws = wred_sum(e);
    if (lane == 0) sred[w] = ws;
    __syncthreads();
    float sum = sred[0] + sred[1] + sred[2] + sred[3];
    attn[t] = e / sum;
    __syncthreads();

    const int d = chunk * 256 + t;
    const float* vb = v + (size_t)b * L_ * D_ + d;
    float p = 0.f;
    #pragma unroll 8
    for (int l = 0; l < L_; ++l) p += attn[l] * vb[(size_t)l * D_];
    pout[((size_t)b * 2 + side) * D_ + d] = p;
}

// K3: per batch: cosine similarity of p1, p2.
__global__ __launch_bounds__(256)
void k_cos(const float* __restrict__ pout, float* __restrict__ out)
{
    const int b = blockIdx.x, t = threadIdx.x, lane = t & 63, w = t >> 6;
    const float* p1 = pout + (size_t)b * 2 * D_;
    const float* p2 = p1 + D_;
    float dot = 0.f, n1 = 0.f, n2 = 0.f;
    for (int d = t; d < D_; d += 256) {
        float a = p1[d], c = p2[d];
        dot += a * c; n1 += a * a; n2 += c * c;
    }
    dot = wred_sum(dot); n1 = wred_sum(n1); n2 = wred_sum(n2);
    __shared__ float sd[4], sa[4], sc[4];
    if (lane == 0) { sd[w] = dot; sa[w] = n1; sc[w] = n2; }
    __syncthreads();
    if (t == 0) {
        float dd = sd[0] + sd[1] + sd[2] + sd[3];
        float aa = sa[0] + sa[1] + sa[2] + sa[3];
        float cc = sc[0] + sc[1] + sc[2] + sc[3];
        out[b] = dd / (fmaxf(sqrtf(aa), 1e-8f) * fmaxf(sqrtf(cc), 1e-8f));
    }
}

extern "C" void kernel_launch(void* const* d_in, const int* in_sizes, int n_in,
                              void* d_out, int out_size, void* d_ws, size_t ws_size,
                              hipStream_t stream)
{
    const float* v1 = (const float*)d_in[0];
    const float* m1 = (const float*)d_in[1];
    const float* v2 = (const float*)d_in[2];
    const float* m2 = (const float*)d_in[3];
    float* out = (float*)d_out;

    unsigned* ru1 = (unsigned*)d_ws;                  // [B, L] mapped row-max (side 1)
    unsigned* ru2 = ru1 + (size_t)B_ * L_;            // [B, L] mapped col-max (side 2)
    float*    pout = (float*)(ru2 + (size_t)B_ * L_); // [B, 2, D] pooled vectors

    hipMemsetAsync(d_ws, 0, 2 * (size_t)B_ * L_ * sizeof(unsigned), stream);

    k_match_max<<<dim3((L_ / BT) * (L_ / BT) * B_), 512, 0, stream>>>(v1, m1, v2, m2, ru1, ru2);

    k_attn_pool<<<dim3(B_ * 2 * 3), 256, 0, stream>>>(v1, m1, v2, m2, ru1, ru2, pout);

    k_cos<<<B_, 256, 0, stream>>>(pout, out);
}

// Round 5
// 77.326 us; speedup vs baseline: 1.7486x; 1.0382x over previous
//
#include <hip/hip_runtime.h>

// ParaModel_69664369541839: match = v1 @ v2^T [B,L1,L2]; masked row/col max;
// s = -max/100 masked; softmax; attention-pool p1,p2; cosine(p1,p2).
// B=128, L1=L2=256, D=768, fp32 in/out.
//
// R5 == R4 with the cvt_pkrtz type fix (__fp16 vec2, not _Float16 vec2).
// K1 staging via __builtin_amdgcn_global_load_lds (width 16, async DMA,
// no VGPR round-trip — R2/R3's register prefetch was repeatedly killed by the
// register allocator, leaving the kernel latency-bound at 1.1TB/s).
// T3 "minimum 2-phase": STAGE(next)->ds_read/cvt/MFMA(cur)->syncthreads.
// fp32 tiles in LDS, linear DMA dest + XOR-swizzled global SOURCE (rule #21),
// same XOR on ds_read side; fp16 fragments built with v_cvt_pkrtz.

#define B_   128
#define L_   256
#define D_   768
#define NEGV (-10000.0f)

typedef _Float16 f16x8 __attribute__((ext_vector_type(8)));
typedef __fp16   h16x2 __attribute__((ext_vector_type(2)));
typedef float    f32x4 __attribute__((ext_vector_type(4)));

#define BT   128          // l1/l2 tile
#define BK   32           // fp32 k-elems per staged tile (= one MFMA K)
#define NKT  (D_ / BK)    // 24

__device__ __forceinline__ unsigned fmap(float f) {
    unsigned u = __float_as_uint(f);
    return (u & 0x80000000u) ? ~u : (u | 0x80000000u);   // monotone float->uint
}
__device__ __forceinline__ float fdecode(unsigned u) {
    return __uint_as_float((u & 0x80000000u) ? (u ^ 0x80000000u) : ~u);
}
__device__ __forceinline__ float wred_max(float v) {
    #pragma unroll
    for (int o = 32; o; o >>= 1) v = fmaxf(v, __shfl_xor(v, o));
    return v;
}
__device__ __forceinline__ float wred_sum(float v) {
    #pragma unroll
    for (int o = 32; o; o >>= 1) v += __shfl_xor(v, o);
    return v;
}

__device__ __forceinline__ void gll16(const float* g, void* lds) {
    __builtin_amdgcn_global_load_lds(
        (const __attribute__((address_space(1))) void*)g,
        (__attribute__((address_space(3))) void*)lds, 16, 0, 0);
}

__device__ __forceinline__ f16x8 cvt8(float4 a, float4 b) {
    union { h16x2 h2[4]; f16x8 h8; } u;
    u.h2[0] = __builtin_amdgcn_cvt_pkrtz(a.x, a.y);
    u.h2[1] = __builtin_amdgcn_cvt_pkrtz(a.z, a.w);
    u.h2[2] = __builtin_amdgcn_cvt_pkrtz(b.x, b.y);
    u.h2[3] = __builtin_amdgcn_cvt_pkrtz(b.z, b.w);
    return u.h8;
}

// K1: per (b, ti, tj): 128x128 match tile via fp16 MFMA; masked row/col max.
__global__ __launch_bounds__(512, 4)
void k_match_max(const float* __restrict__ v1, const float* __restrict__ m1,
                 const float* __restrict__ v2, const float* __restrict__ m2,
                 unsigned* __restrict__ ru1, unsigned* __restrict__ ru2)
{
    __shared__ __align__(16) float As[2][BT * BK];   // fp32, linear DMA dest
    __shared__ __align__(16) float Bs[2][BT * BK];   // (source pre-swizzled)
    __shared__ unsigned rU[BT], cU[BT];
    __shared__ float m1s[BT], m2s[BT];

    // bijective XCD swizzle: 512 blocks, 64/XCD -> a batch's 4 blocks on one XCD
    const int bid = blockIdx.x;
    const int wg  = (bid & 7) * 64 + (bid >> 3);
    const int b = wg >> 2, ti = (wg >> 1) & 1, tj = wg & 1;

    const int t = threadIdx.x;
    const int lane = t & 63, w = t >> 6;
    const int wr = w >> 1, wc = w & 1;          // wave sub-tile: 32 rows x 64 cols
    const int fr = lane & 15, fg = lane >> 4;

    if (t < BT) {
        rU[t] = 0u; cU[t] = 0u;                 // 0 == -inf under fmap
        m1s[t] = m1[b * L_ + ti * BT + t];
        m2s[t] = m2[b * L_ + tj * BT + t];
    }

    const float* pa = v1 + ((size_t)b * L_ + ti * BT) * D_;
    const float* pb = v2 + ((size_t)b * L_ + tj * BT) * D_;

    // DMA geometry: per operand tile = 128 rows x 32 fp32 = 1024 x 16B.
    // 8 waves x 2 issues; chunk c = w*2+i covers rows 8c..8c+7.
    // Lane l -> LDS (row 8c+(l>>3), 16B-block l&7). Source block XOR'd by row&7
    // so that LDS(row, blk) holds global(row, blk^(row&7)).
    const int r_in = lane >> 3;                  // 0..7, == row&7
    const int sblk = (lane & 7) ^ r_in;          // swizzled source 16B-block
    const int row0 = (w * 2 + 0) * 8 + r_in;
    const int row1 = (w * 2 + 1) * 8 + r_in;
    const float* ga0 = pa + (size_t)row0 * D_ + sblk * 4;
    const float* ga1 = pa + (size_t)row1 * D_ + sblk * 4;
    const float* gb0 = pb + (size_t)row0 * D_ + sblk * 4;
    const float* gb1 = pb + (size_t)row1 * D_ + sblk * 4;

    #define STAGE(buf, kt) do {                                   \
        int ko = (kt) * BK;                                       \
        gll16(ga0 + ko, &As[buf][(w * 2 + 0) * 256]);             \
        gll16(ga1 + ko, &As[buf][(w * 2 + 1) * 256]);             \
        gll16(gb0 + ko, &Bs[buf][(w * 2 + 0) * 256]);             \
        gll16(gb1 + ko, &Bs[buf][(w * 2 + 1) * 256]);             \
    } while (0)

    f32x4 acc[2][4] = {};
    STAGE(0, 0);
    __syncthreads();                             // drains stage(0) + LDS init
    int cur = 0;
    for (int kt = 0; kt < NKT; ++kt) {
        if (kt + 1 < NKT) STAGE(cur ^ 1, kt + 1);   // async DMA under compute
        f16x8 af[2], bf[4];
        #pragma unroll
        for (int i = 0; i < 2; ++i) {
            int r1 = wr * 32 + i * 16 + fr;          // r1&7 == fr&7
            const float* base = &As[cur][r1 * BK];
            float4 x = *(const float4*)(base + (((2 * fg + 0) ^ (fr & 7)) << 2));
            float4 y = *(const float4*)(base + (((2 * fg + 1) ^ (fr & 7)) << 2));
            af[i] = cvt8(x, y);
        }
        #pragma unroll
        for (int j = 0; j < 4; ++j) {
            int r2 = wc * 64 + j * 16 + fr;          // r2&7 == fr&7
            const float* base = &Bs[cur][r2 * BK];
            float4 x = *(const float4*)(base + (((2 * fg + 0) ^ (fr & 7)) << 2));
            float4 y = *(const float4*)(base + (((2 * fg + 1) ^ (fr & 7)) << 2));
            bf[j] = cvt8(x, y);
        }
        #pragma unroll
        for (int i = 0; i < 2; ++i)
            #pragma unroll
            for (int j = 0; j < 4; ++j)
                acc[i][j] = __builtin_amdgcn_mfma_f32_16x16x32_f16(af[i], bf[j], acc[i][j], 0, 0, 0);
        __syncthreads();                         // vmcnt(0)+lgkmcnt(0)+barrier
        cur ^= 1;
    }
    #undef STAGE

    // masked row-max: C/D layout row = fg*4+reg (+16i), col = fr (+16j)
    #pragma unroll
    for (int i = 0; i < 2; ++i)
        #pragma unroll
        for (int r = 0; r < 4; ++r) {
            int row = wr * 32 + i * 16 + fg * 4 + r;
            bool rv = m1s[row] > 0.f;
            float mx = NEGV;
            #pragma unroll
            for (int j = 0; j < 4; ++j) {
                int col = wc * 64 + j * 16 + fr;
                float vv = (rv && m2s[col] > 0.f) ? acc[i][j][r] : NEGV;
                mx = fmaxf(mx, vv);
            }
            atomicMax(&rU[row], fmap(mx));
        }
    // masked col-max
    #pragma unroll
    for (int j = 0; j < 4; ++j) {
        int col = wc * 64 + j * 16 + fr;
        bool cv = m2s[col] > 0.f;
        float mx = NEGV;
        #pragma unroll
        for (int i = 0; i < 2; ++i)
            #pragma unroll
            for (int r = 0; r < 4; ++r) {
                int row = wr * 32 + i * 16 + fg * 4 + r;
                float vv = (cv && m1s[row] > 0.f) ? acc[i][j][r] : NEGV;
                mx = fmaxf(mx, vv);
            }
        atomicMax(&cU[col], fmap(mx));
    }
    __syncthreads();
    if (t < BT)            atomicMax(&ru1[b * L_ + ti * BT + t], rU[t]);
    else if (t < 2 * BT)   atomicMax(&ru2[b * L_ + tj * BT + (t - BT)], cU[t - BT]);
}

// K2: per (b, side, chunk): softmax over 256 logits (redundant per chunk, cheap)
// + pool of 256 cols. 768 blocks.
__global__ __launch_bounds__(256)
void k_attn_pool(const float* __restrict__ v1, const float* __restrict__ m1,
                 const float* __restrict__ v2, const float* __restrict__ m2,
                 const unsigned* __restrict__ ru1, const unsigned* __restrict__ ru2,
                 float* __restrict__ pout)
{
    // XCD swizzle: 768 blocks -> 96/XCD -> 16 consecutive batches per XCD
    const int lin = (int)blockIdx.x;
    const int swz = (lin & 7) * 96 + (lin >> 3);
    const int b = swz / 6, rem = swz % 6, side = rem / 3, chunk = rem % 3;

    const float* v     = side ? v2 : v1;
    const float* mk    = side ? m2 : m1;
    const unsigned* ru = side ? ru2 : ru1;
    const int t = threadIdx.x, lane = t & 63, w = t >> 6;

    __shared__ float attn[L_];
    __shared__ float sred[4];

    float mkv = mk[b * L_ + t];
    float s = (mkv > 0.f) ? (-fdecode(ru[b * L_ + t]) / 100.0f) : NEGV;

    float wm = wred_max(s);
    if (lane == 0) sred[w] = wm;
    __syncthreads();
    float mx = fmaxf(fmaxf(sred[0], sred[1]), fmaxf(sred[2], sred[3]));
    float e = expf(s - mx);
    __syncthreads();
    float ws = wred_sum(e);
    if (lane == 0) sred[w] = ws;
    __syncthreads();
    float sum = sred[0] + sred[1] + sred[2] + sred[3];
    attn[t] = e / sum;
    __syncthreads();

    const int d = chunk * 256 + t;
    const float* vb = v + (size_t)b * L_ * D_ + d;
    float p = 0.f;
    #pragma unroll 8
    for (int l = 0; l < L_; ++l) p += attn[l] * vb[(size_t)l * D_];
    pout[((size_t)b * 2 + side) * D_ + d] = p;
}

// K3: per batch: cosine similarity of p1, p2.
__global__ __launch_bounds__(256)
void k_cos(const float* __restrict__ pout, float* __restrict__ out)
{
    const int b = blockIdx.x, t = threadIdx.x, lane = t & 63, w = t >> 6;
    const float* p1 = pout + (size_t)b * 2 * D_;
    const float* p2 = p1 + D_;
    float dot = 0.f, n1 = 0.f, n2 = 0.f;
    for (int d = t; d < D_; d += 256) {
        float a = p1[d], c = p2[d];
        dot += a * c; n1 += a * a; n2 += c * c;
    }
    dot = wred_sum(dot); n1 = wred_sum(n1); n2 = wred_sum(n2);
    __shared__ float sd[4], sa[4], sc[4];
    if (lane == 0) { sd[w] = dot; sa[w] = n1; sc[w] = n2; }
    __syncthreads();
    if (t == 0) {
        float dd = sd[0] + sd[1] + sd[2] + sd[3];
        float aa = sa[0] + sa[1] + sa[2] + sa[3];
        float cc = sc[0] + sc[1] + sc[2] + sc[3];
        out[b] = dd / (fmaxf(sqrtf(aa), 1e-8f) * fmaxf(sqrtf(cc), 1e-8f));
    }
}

extern "C" void kernel_launch(void* const* d_in, const int* in_sizes, int n_in,
                              void* d_out, int out_size, void* d_ws, size_t ws_size,
                              hipStream_t stream)
{
    const float* v1 = (const float*)d_in[0];
    const float* m1 = (const float*)d_in[1];
    const float* v2 = (const float*)d_in[2];
    const float* m2 = (const float*)d_in[3];
    float* out = (float*)d_out;

    unsigned* ru1 = (unsigned*)d_ws;                  // [B, L] mapped row-max (side 1)
    unsigned* ru2 = ru1 + (size_t)B_ * L_;            // [B, L] mapped col-max (side 2)
    float*    pout = (float*)(ru2 + (size_t)B_ * L_); // [B, 2, D] pooled vectors

    (void)hipMemsetAsync(d_ws, 0, 2 * (size_t)B_ * L_ * sizeof(unsigned), stream);

    k_match_max<<<dim3((L_ / BT) * (L_ / BT) * B_), 512, 0, stream>>>(v1, m1, v2, m2, ru1, ru2);

    k_attn_pool<<<dim3(B_ * 2 * 3), 256, 0, stream>>>(v1, m1, v2, m2, ru1, ru2, pout);

    k_cos<<<B_, 256, 0, stream>>>(pout, out);
}